// Round 1
// baseline (615.666 us; speedup 1.0000x reference)
//
#include <hip/hip_runtime.h>

// AttentionBlock: x[4,2048,1024] fp32; q=x@wq, k=x@wk, v=x@wv;
// scores=q@k^T (NO 1/sqrt(d) scale); softmax; out=P@v.
// Precision: scores ~N(0,32768^2), softmax is near-argmax -> need ~fp32-level
// score accuracy. Use split-fp16 (hi+lo) 3-term MFMA for projections+QK^T.
// PV is plain fp16 MFMA (output-level error ~0.1 << threshold 3.38).

typedef _Float16 half4_t __attribute__((ext_vector_type(4)));
typedef _Float16 half8_t __attribute__((ext_vector_type(8)));
typedef float f32x4 __attribute__((ext_vector_type(4)));

#define BM 128
#define BN 128
#define BK 32
#define PAD 56  // f16 elems per LDS row: 112 B = 16B-aligned, 28-word stride -> 2-way bank max

// C[M][N] = A[M][K] * B, fp32 in/out.
// BTRANS=false: B given as [N][K] row-major (k-contiguous, e.g. scores vs k-rows).
// BTRANS=true : B given as [K][N] row-major (e.g. weights, v) -> transpose-stage into LDS.
// SPLIT=true  : split-fp16 (hi+lo) 3-MFMA per pair; false: plain fp16 1-MFMA.
template <bool SPLIT, bool BTRANS>
__global__ __launch_bounds__(256, 2) void gemm_kernel(
    const float* __restrict__ Ag, const float* __restrict__ Bg,
    float* __restrict__ Cg, int lda, int ldb, int ldc, int K,
    size_t strA, size_t strB, size_t strC)
{
    const float* A = Ag + (size_t)blockIdx.z * strA;
    const float* B = Bg + (size_t)blockIdx.z * strB;
    float* C = Cg + (size_t)blockIdx.z * strC;

    __shared__ __align__(16) _Float16 shA[SPLIT ? 2 : 1][BM][PAD];
    __shared__ __align__(16) _Float16 shB[SPLIT ? 2 : 1][BN][PAD];

    const int tid = threadIdx.x;
    const int wave = tid >> 6, lane = tid & 63;
    const int wm = (wave >> 1) * 64, wn = (wave & 1) * 64;  // 2x2 waves, 64x64 each
    const int lrow = lane & 15, quad = lane >> 4;

    const int bm = blockIdx.y * BM, bn = blockIdx.x * BN;

    f32x4 acc[4][4];
#pragma unroll
    for (int i = 0; i < 4; ++i)
#pragma unroll
        for (int j = 0; j < 4; ++j) acc[i][j] = 0.0f;

    for (int k0 = 0; k0 < K; k0 += BK) {
        // ---- stage A: [BM][BK] fp32 -> hi/lo f16 planes (k-contiguous rows)
#pragma unroll
        for (int i = 0; i < 4; ++i) {
            int f = tid + 256 * i;
            int r = f >> 3, c4 = (f & 7) * 4;
            float4 x = *(const float4*)(A + (size_t)(bm + r) * lda + k0 + c4);
            float xs[4] = {x.x, x.y, x.z, x.w};
            half4_t h, l;
#pragma unroll
            for (int j = 0; j < 4; ++j) {
                _Float16 hh = (_Float16)xs[j];
                h[j] = hh;
                if (SPLIT) l[j] = (_Float16)(xs[j] - (float)hh);
            }
            *(half4_t*)&shA[0][r][c4] = h;
            if (SPLIT) *(half4_t*)&shA[1][r][c4] = l;
        }
        // ---- stage B into LDS as [BN][BK] (k-contiguous)
        if (!BTRANS) {
#pragma unroll
            for (int i = 0; i < 4; ++i) {
                int f = tid + 256 * i;
                int r = f >> 3, c4 = (f & 7) * 4;
                float4 x = *(const float4*)(B + (size_t)(bn + r) * ldb + k0 + c4);
                float xs[4] = {x.x, x.y, x.z, x.w};
                half4_t h, l;
#pragma unroll
                for (int j = 0; j < 4; ++j) {
                    _Float16 hh = (_Float16)xs[j];
                    h[j] = hh;
                    if (SPLIT) l[j] = (_Float16)(xs[j] - (float)hh);
                }
                *(half4_t*)&shB[0][r][c4] = h;
                if (SPLIT) *(half4_t*)&shB[1][r][c4] = l;
            }
        } else {
            // B global is [K][N]; gather 4 k's per n (reads coalesced along n)
#pragma unroll
            for (int i = 0; i < 4; ++i) {
                int f = tid + 256 * i;
                int n = f & 127, kq = (f >> 7) * 4;
                half4_t h, l;
#pragma unroll
                for (int j = 0; j < 4; ++j) {
                    float xv = B[(size_t)(k0 + kq + j) * ldb + bn + n];
                    _Float16 hh = (_Float16)xv;
                    h[j] = hh;
                    if (SPLIT) l[j] = (_Float16)(xv - (float)hh);
                }
                *(half4_t*)&shB[0][n][kq] = h;
                if (SPLIT) *(half4_t*)&shB[1][n][kq] = l;
            }
        }
        __syncthreads();

        // ---- fragments + MFMA (16x16x32 f16; BK=32 = one k-step)
        half8_t a0[4], a1[4], b0[4], b1[4];
#pragma unroll
        for (int mt = 0; mt < 4; ++mt) {
            a0[mt] = *(const half8_t*)&shA[0][wm + mt * 16 + lrow][quad * 8];
            if (SPLIT) a1[mt] = *(const half8_t*)&shA[1][wm + mt * 16 + lrow][quad * 8];
        }
#pragma unroll
        for (int nt = 0; nt < 4; ++nt) {
            b0[nt] = *(const half8_t*)&shB[0][wn + nt * 16 + lrow][quad * 8];
            if (SPLIT) b1[nt] = *(const half8_t*)&shB[1][wn + nt * 16 + lrow][quad * 8];
        }
#pragma unroll
        for (int mt = 0; mt < 4; ++mt)
#pragma unroll
            for (int nt = 0; nt < 4; ++nt) {
                acc[mt][nt] = __builtin_amdgcn_mfma_f32_16x16x32_f16(a0[mt], b0[nt], acc[mt][nt], 0, 0, 0);
                if (SPLIT) {
                    acc[mt][nt] = __builtin_amdgcn_mfma_f32_16x16x32_f16(a0[mt], b1[nt], acc[mt][nt], 0, 0, 0);
                    acc[mt][nt] = __builtin_amdgcn_mfma_f32_16x16x32_f16(a1[mt], b0[nt], acc[mt][nt], 0, 0, 0);
                }
            }
        __syncthreads();
    }

    // ---- epilogue: C/D layout col=lane&15, row=quad*4+reg (m89-verified)
#pragma unroll
    for (int mt = 0; mt < 4; ++mt)
#pragma unroll
        for (int nt = 0; nt < 4; ++nt)
#pragma unroll
            for (int r = 0; r < 4; ++r)
                C[(size_t)(bm + wm + mt * 16 + quad * 4 + r) * ldc + bn + wn + nt * 16 + lrow] =
                    acc[mt][nt][r];
}

// In-place row softmax over 2048 fp32 columns; one block (256 thr) per row.
__global__ __launch_bounds__(256) void softmax_kernel(float* __restrict__ S)
{
    float* row = S + (size_t)blockIdx.x * 2048;
    float4* r4 = (float4*)row;
    const int tid = threadIdx.x;
    const int wave = tid >> 6, lane = tid & 63;

    float4 a = r4[tid], b = r4[tid + 256];
    float m = fmaxf(fmaxf(fmaxf(a.x, a.y), fmaxf(a.z, a.w)),
                    fmaxf(fmaxf(b.x, b.y), fmaxf(b.z, b.w)));
#pragma unroll
    for (int o = 32; o; o >>= 1) m = fmaxf(m, __shfl_xor(m, o));
    __shared__ float redm[4];
    __shared__ float reds[4];
    if (lane == 0) redm[wave] = m;
    __syncthreads();
    m = fmaxf(fmaxf(redm[0], redm[1]), fmaxf(redm[2], redm[3]));

    a.x = __expf(a.x - m); a.y = __expf(a.y - m);
    a.z = __expf(a.z - m); a.w = __expf(a.w - m);
    b.x = __expf(b.x - m); b.y = __expf(b.y - m);
    b.z = __expf(b.z - m); b.w = __expf(b.w - m);

    float s = a.x + a.y + a.z + a.w + b.x + b.y + b.z + b.w;
#pragma unroll
    for (int o = 32; o; o >>= 1) s += __shfl_xor(s, o);
    if (lane == 0) reds[wave] = s;
    __syncthreads();
    s = reds[0] + reds[1] + reds[2] + reds[3];

    float inv = 1.0f / s;
    a.x *= inv; a.y *= inv; a.z *= inv; a.w *= inv;
    b.x *= inv; b.y *= inv; b.z *= inv; b.w *= inv;
    r4[tid] = a;
    r4[tid + 256] = b;
}

extern "C" void kernel_launch(void* const* d_in, const int* in_sizes, int n_in,
                              void* d_out, int out_size, void* d_ws, size_t ws_size,
                              hipStream_t stream)
{
    const float* x  = (const float*)d_in[0];
    const float* wq = (const float*)d_in[1];
    const float* wk = (const float*)d_in[2];
    const float* wv = (const float*)d_in[3];
    float* out = (float*)d_out;

    const int Bb = 4, S = 2048, D = 1024;
    const size_t MS = (size_t)Bb * S;  // 8192

    // ws layout (fp32): q,k,v [8192x1024] + scores [4x2048x2048] = 160 MB
    float* q  = (float*)d_ws;
    float* k  = q + MS * D;
    float* v  = k + MS * D;
    float* sc = v + MS * D;

    dim3 blk(256);

    // QKV projections: C[s][e] = sum_d x[s][d] * w[d][e]  (B is [K][N] -> BTRANS)
    gemm_kernel<true, true><<<dim3(D / BN, MS / BM, 1), blk, 0, stream>>>(
        x, wq, q, D, D, D, D, 0, 0, 0);
    gemm_kernel<true, true><<<dim3(D / BN, MS / BM, 1), blk, 0, stream>>>(
        x, wk, k, D, D, D, D, 0, 0, 0);
    gemm_kernel<true, true><<<dim3(D / BN, MS / BM, 1), blk, 0, stream>>>(
        x, wv, v, D, D, D, D, 0, 0, 0);

    // scores[b][s][t] = sum_d q[b,s,d] * k[b,t,d]   (B is [N][K] -> natural)
    gemm_kernel<true, false><<<dim3(S / BN, S / BM, Bb), blk, 0, stream>>>(
        q, k, sc, D, D, S, D, (size_t)S * D, (size_t)S * D, (size_t)S * S);

    // softmax rows (in place)
    softmax_kernel<<<dim3(Bb * S), blk, 0, stream>>>(sc);

    // out[b][s][e] = sum_t P[b,s,t] * v[b,t,e]  (B is [K][N] -> BTRANS, plain fp16)
    gemm_kernel<false, true><<<dim3(D / BN, S / BM, Bb), blk, 0, stream>>>(
        sc, v, out, S, D, D, S, (size_t)S * S, (size_t)S * D, (size_t)S * D);
}

// Round 2
// 435.915 us; speedup vs baseline: 1.4124x; 1.4124x over previous
//
#include <hip/hip_runtime.h>

// AttentionBlock: x[4,2048,1024] fp32; q=x@wq, k=x@wk, v=x@wv;
// scores=q@k^T (NO scale); softmax; out=P@v.
// Precision: split-f16 (hi+lo, 3-MFMA) for q/k projections and QK^T;
// plain f16 for v projection and PV. All conversions hoisted OUT of k-loops:
// pre-converted f16 operands everywhere, staged via global_load_lds width=16.

typedef _Float16 half4_t __attribute__((ext_vector_type(4)));
typedef _Float16 half8_t __attribute__((ext_vector_type(8)));
typedef float f32x4 __attribute__((ext_vector_type(4)));

#define BM 128
#define BN 128
#define BK 32

// async 16B global -> LDS (DMA, no VGPR round trip). LDS dest must be
// wave-uniform base + lane*16 — our staging pattern guarantees that.
__device__ __forceinline__ void gl_lds16(const _Float16* g, _Float16* l) {
    __builtin_amdgcn_global_load_lds(
        (const __attribute__((address_space(1))) unsigned int*)g,
        (__attribute__((address_space(3))) unsigned int*)l, 16, 0, 0);
}

// ---------------- conversion kernels ----------------

// x fp32 -> hi/lo f16 planes (same layout)
__global__ __launch_bounds__(256) void conv_x_kernel(
    const float* __restrict__ in, _Float16* __restrict__ hi,
    _Float16* __restrict__ lo, int n4)
{
    int i = blockIdx.x * 256 + threadIdx.x;
    if (i >= n4) return;
    float4 v = ((const float4*)in)[i];
    float xs[4] = {v.x, v.y, v.z, v.w};
    half4_t h, l;
#pragma unroll
    for (int j = 0; j < 4; ++j) {
        _Float16 hh = (_Float16)xs[j];
        h[j] = hh;
        l[j] = (_Float16)(xs[j] - (float)hh);
    }
    ((half4_t*)hi)[i] = h;
    ((half4_t*)lo)[i] = l;
}

// w [1024][1024] fp32 -> wT [1024][1024] f16 hi (+lo for q,k). 64x64 LDS tiles.
__global__ __launch_bounds__(256) void conv_w_kernel(
    const float* __restrict__ wq, const float* __restrict__ wk,
    const float* __restrict__ wv, _Float16* qh, _Float16* ql,
    _Float16* kh, _Float16* kl, _Float16* vh)
{
    __shared__ float tle[64][65];
    const int z = blockIdx.z;
    const float* w = (z == 0) ? wq : (z == 1) ? wk : wv;
    _Float16* oh = (z == 0) ? qh : (z == 1) ? kh : vh;
    _Float16* ol = (z == 0) ? ql : (z == 1) ? kl : nullptr;
    const int tr = blockIdx.y * 64, tc = blockIdx.x * 64;
    const int t16 = threadIdx.x & 15, tq = threadIdx.x >> 4;
#pragma unroll
    for (int j = 0; j < 4; ++j) {
        int lr = tq + j * 16;
        float4 v = *(const float4*)(w + (size_t)(tr + lr) * 1024 + tc + t16 * 4);
        tle[lr][t16 * 4 + 0] = v.x;
        tle[lr][t16 * 4 + 1] = v.y;
        tle[lr][t16 * 4 + 2] = v.z;
        tle[lr][t16 * 4 + 3] = v.w;
    }
    __syncthreads();
#pragma unroll
    for (int j = 0; j < 4; ++j) {
        int orow = tq + j * 16;   // col index within tile -> out row
        int oc = t16 * 4;         // row index within tile -> out col
        half4_t h, l;
#pragma unroll
        for (int i = 0; i < 4; ++i) {
            float xv = tle[oc + i][orow];
            _Float16 hh = (_Float16)xv;
            h[i] = hh;
            l[i] = (_Float16)(xv - (float)hh);
        }
        *(half4_t*)(oh + (size_t)(tc + orow) * 1024 + tr + oc) = h;
        if (ol) *(half4_t*)(ol + (size_t)(tc + orow) * 1024 + tr + oc) = l;
    }
}

// ---------------- split-f16 GEMM (3-MFMA) ----------------
// A planes [M][K] f16, B planes [N][K] f16 (k-contiguous both).
// OUTF32: write fp32 C. else: write f16 hi/lo pair (split epilogue).
template <bool OUTF32>
__global__ __launch_bounds__(256) void gemm_split(
    const _Float16* __restrict__ Ah, const _Float16* __restrict__ Al, size_t az,
    const _Float16* __restrict__ Bh, const _Float16* __restrict__ Bl, size_t bz,
    float* __restrict__ Cf, size_t cz, int ldc,
    _Float16* __restrict__ Oh, _Float16* __restrict__ Ol, size_t oz, int ldo,
    int lda, int ldb, int K)
{
    __shared__ __align__(16) _Float16 sAh[BM][BK], sAl[BM][BK];
    __shared__ __align__(16) _Float16 sBh[BN][BK], sBl[BN][BK];

    const int tid = threadIdx.x;
    const int wave = tid >> 6, lane = tid & 63;
    const int wm = (wave >> 1) * 64, wn = (wave & 1) * 64;
    const int lrow = lane & 15, quad = lane >> 4;
    const int bm = blockIdx.y * BM, bn = blockIdx.x * BN;
    const int z = blockIdx.z;

    const _Float16* pAh = Ah + (size_t)z * az;
    const _Float16* pAl = Al + (size_t)z * az;
    const _Float16* pBh = Bh + (size_t)z * bz;
    const _Float16* pBl = Bl + (size_t)z * bz;

    // staging: wave w covers rows [32w, 32w+32) of each tile; lane l covers
    // row 32w + l/4 (+16), k-offset (l&3)*8. LDS dest = base + 16*lane bytes.
    const int r0 = wave * 32 + (lane >> 2);
    const int kofs = (lane & 3) * 8;
    const size_t a0o = (size_t)(bm + r0) * lda + kofs;
    const size_t a1o = a0o + (size_t)16 * lda;
    const size_t b0o = (size_t)(bn + r0) * ldb + kofs;
    const size_t b1o = b0o + (size_t)16 * ldb;
    _Float16* lA0 = &sAh[r0][kofs];
    _Float16* lA1 = &sAh[r0 + 16][kofs];
    _Float16* lAl0 = &sAl[r0][kofs];
    _Float16* lAl1 = &sAl[r0 + 16][kofs];
    _Float16* lB0 = &sBh[r0][kofs];
    _Float16* lB1 = &sBh[r0 + 16][kofs];
    _Float16* lBl0 = &sBl[r0][kofs];
    _Float16* lBl1 = &sBl[r0 + 16][kofs];

    f32x4 acc[4][4];
#pragma unroll
    for (int i = 0; i < 4; ++i)
#pragma unroll
        for (int j = 0; j < 4; ++j) acc[i][j] = 0.0f;

    for (int k0 = 0; k0 < K; k0 += BK) {
        gl_lds16(pAh + a0o + k0, lA0);
        gl_lds16(pAh + a1o + k0, lA1);
        gl_lds16(pAl + a0o + k0, lAl0);
        gl_lds16(pAl + a1o + k0, lAl1);
        gl_lds16(pBh + b0o + k0, lB0);
        gl_lds16(pBh + b1o + k0, lB1);
        gl_lds16(pBl + b0o + k0, lBl0);
        gl_lds16(pBl + b1o + k0, lBl1);
        __syncthreads();

        half8_t a0[4], a1[4], b0[4], b1[4];
#pragma unroll
        for (int mt = 0; mt < 4; ++mt) {
            a0[mt] = *(const half8_t*)&sAh[wm + mt * 16 + lrow][quad * 8];
            a1[mt] = *(const half8_t*)&sAl[wm + mt * 16 + lrow][quad * 8];
        }
#pragma unroll
        for (int nt = 0; nt < 4; ++nt) {
            b0[nt] = *(const half8_t*)&sBh[wn + nt * 16 + lrow][quad * 8];
            b1[nt] = *(const half8_t*)&sBl[wn + nt * 16 + lrow][quad * 8];
        }
#pragma unroll
        for (int mt = 0; mt < 4; ++mt)
#pragma unroll
            for (int nt = 0; nt < 4; ++nt) {
                acc[mt][nt] = __builtin_amdgcn_mfma_f32_16x16x32_f16(a0[mt], b0[nt], acc[mt][nt], 0, 0, 0);
                acc[mt][nt] = __builtin_amdgcn_mfma_f32_16x16x32_f16(a0[mt], b1[nt], acc[mt][nt], 0, 0, 0);
                acc[mt][nt] = __builtin_amdgcn_mfma_f32_16x16x32_f16(a1[mt], b0[nt], acc[mt][nt], 0, 0, 0);
            }
        __syncthreads();
    }

    // epilogue: C/D layout col=lane&15, row=quad*4+r
#pragma unroll
    for (int mt = 0; mt < 4; ++mt)
#pragma unroll
        for (int nt = 0; nt < 4; ++nt)
#pragma unroll
            for (int r = 0; r < 4; ++r) {
                int gm = bm + wm + mt * 16 + quad * 4 + r;
                int gn = bn + wn + nt * 16 + lrow;
                float v = acc[mt][nt][r];
                if (OUTF32) {
                    Cf[(size_t)z * cz + (size_t)gm * ldc + gn] = v;
                } else {
                    _Float16 h = (_Float16)v;
                    Oh[(size_t)z * oz + (size_t)gm * ldo + gn] = h;
                    Ol[(size_t)z * oz + (size_t)gm * ldo + gn] = (_Float16)(v - (float)h);
                }
            }
}

// ---------------- plain-f16 GEMM ----------------
// A [M][K] f16, B [N][K] f16. TRANSOUT: write f16 C^T per-batch as
// vT[b][n][t] (b = gm>>11, t = gm&2047); else write fp32 C row-major.
template <bool TRANSOUT>
__global__ __launch_bounds__(256) void gemm_plain(
    const _Float16* __restrict__ Ag, size_t az,
    const _Float16* __restrict__ Bg, size_t bz,
    float* __restrict__ Cf, size_t cz, int ldc,
    _Float16* __restrict__ Ot,
    int lda, int ldb, int K)
{
    __shared__ __align__(16) _Float16 sA[BM][BK], sB[BN][BK];

    const int tid = threadIdx.x;
    const int wave = tid >> 6, lane = tid & 63;
    const int wm = (wave >> 1) * 64, wn = (wave & 1) * 64;
    const int lrow = lane & 15, quad = lane >> 4;
    const int bm = blockIdx.y * BM, bn = blockIdx.x * BN;
    const int z = blockIdx.z;

    const _Float16* pA = Ag + (size_t)z * az;
    const _Float16* pB = Bg + (size_t)z * bz;

    const int r0 = wave * 32 + (lane >> 2);
    const int kofs = (lane & 3) * 8;
    const size_t a0o = (size_t)(bm + r0) * lda + kofs;
    const size_t a1o = a0o + (size_t)16 * lda;
    const size_t b0o = (size_t)(bn + r0) * ldb + kofs;
    const size_t b1o = b0o + (size_t)16 * ldb;
    _Float16* lA0 = &sA[r0][kofs];
    _Float16* lA1 = &sA[r0 + 16][kofs];
    _Float16* lB0 = &sB[r0][kofs];
    _Float16* lB1 = &sB[r0 + 16][kofs];

    f32x4 acc[4][4];
#pragma unroll
    for (int i = 0; i < 4; ++i)
#pragma unroll
        for (int j = 0; j < 4; ++j) acc[i][j] = 0.0f;

    for (int k0 = 0; k0 < K; k0 += BK) {
        gl_lds16(pA + a0o + k0, lA0);
        gl_lds16(pA + a1o + k0, lA1);
        gl_lds16(pB + b0o + k0, lB0);
        gl_lds16(pB + b1o + k0, lB1);
        __syncthreads();

        half8_t a0[4], b0[4];
#pragma unroll
        for (int mt = 0; mt < 4; ++mt)
            a0[mt] = *(const half8_t*)&sA[wm + mt * 16 + lrow][quad * 8];
#pragma unroll
        for (int nt = 0; nt < 4; ++nt)
            b0[nt] = *(const half8_t*)&sB[wn + nt * 16 + lrow][quad * 8];
#pragma unroll
        for (int mt = 0; mt < 4; ++mt)
#pragma unroll
            for (int nt = 0; nt < 4; ++nt)
                acc[mt][nt] = __builtin_amdgcn_mfma_f32_16x16x32_f16(a0[mt], b0[nt], acc[mt][nt], 0, 0, 0);
        __syncthreads();
    }

#pragma unroll
    for (int mt = 0; mt < 4; ++mt)
#pragma unroll
        for (int nt = 0; nt < 4; ++nt) {
            int gm0 = bm + wm + mt * 16 + quad * 4;
            int gn = bn + wn + nt * 16 + lrow;
            if (TRANSOUT) {
                // vT[b][gn][t0..t0+3], b = gm0>>11, t0 = gm0&2047 (contiguous)
                half4_t o;
#pragma unroll
                for (int r = 0; r < 4; ++r) o[r] = (_Float16)acc[mt][nt][r];
                *(half4_t*)(Ot + ((size_t)(gm0 >> 11) << 21) +
                            (size_t)gn * 2048 + (gm0 & 2047)) = o;
            } else {
#pragma unroll
                for (int r = 0; r < 4; ++r)
                    Cf[(size_t)z * cz + (size_t)(gm0 + r) * ldc + gn] = acc[mt][nt][r];
            }
        }
}

// ---------------- softmax: fp32 scores row -> f16 P row, in place ----------------
__global__ __launch_bounds__(256) void softmax_kernel(float* __restrict__ S)
{
    float* row = S + (size_t)blockIdx.x * 2048;
    float4* r4 = (float4*)row;
    const int tid = threadIdx.x;
    const int wave = tid >> 6, lane = tid & 63;

    float4 a = r4[tid], b = r4[tid + 256];
    float m = fmaxf(fmaxf(fmaxf(a.x, a.y), fmaxf(a.z, a.w)),
                    fmaxf(fmaxf(b.x, b.y), fmaxf(b.z, b.w)));
#pragma unroll
    for (int o = 32; o; o >>= 1) m = fmaxf(m, __shfl_xor(m, o));
    __shared__ float redm[4];
    __shared__ float reds[4];
    if (lane == 0) redm[wave] = m;
    __syncthreads();
    m = fmaxf(fmaxf(redm[0], redm[1]), fmaxf(redm[2], redm[3]));

    a.x = __expf(a.x - m); a.y = __expf(a.y - m);
    a.z = __expf(a.z - m); a.w = __expf(a.w - m);
    b.x = __expf(b.x - m); b.y = __expf(b.y - m);
    b.z = __expf(b.z - m); b.w = __expf(b.w - m);

    float s = a.x + a.y + a.z + a.w + b.x + b.y + b.z + b.w;
#pragma unroll
    for (int o = 32; o; o >>= 1) s += __shfl_xor(s, o);
    if (lane == 0) reds[wave] = s;
    __syncthreads();   // also orders all row loads before the f16 overwrite below
    s = reds[0] + reds[1] + reds[2] + reds[3];

    float inv = 1.0f / s;
    _Float16* o16 = (_Float16*)row;
    half4_t ha, hb;
    ha[0] = (_Float16)(a.x * inv); ha[1] = (_Float16)(a.y * inv);
    ha[2] = (_Float16)(a.z * inv); ha[3] = (_Float16)(a.w * inv);
    hb[0] = (_Float16)(b.x * inv); hb[1] = (_Float16)(b.y * inv);
    hb[2] = (_Float16)(b.z * inv); hb[3] = (_Float16)(b.w * inv);
    ((half4_t*)o16)[tid] = ha;
    ((half4_t*)o16)[tid + 256] = hb;
}

extern "C" void kernel_launch(void* const* d_in, const int* in_sizes, int n_in,
                              void* d_out, int out_size, void* d_ws, size_t ws_size,
                              hipStream_t stream)
{
    const float* x  = (const float*)d_in[0];
    const float* wq = (const float*)d_in[1];
    const float* wk = (const float*)d_in[2];
    const float* wv = (const float*)d_in[3];
    float* out = (float*)d_out;

    const int S = 2048, D = 1024;
    const size_t M8 = 8ull << 20;  // 8M elems (8192x1024)
    const size_t M1 = 1ull << 20;  // 1M elems (1024x1024)
    char* ws = (char*)d_ws;

    // ws layout (bytes). sc (fp32, 64MB) overlays xh/xl/w region (dead by then).
    _Float16* qh  = (_Float16*)(ws);                  // 16 MB
    _Float16* kh  = (_Float16*)(ws + (16ull << 20));  // 16 MB
    _Float16* ql  = (_Float16*)(ws + (32ull << 20));  // 16 MB
    _Float16* kl  = (_Float16*)(ws + (48ull << 20));  // 16 MB
    _Float16* vT  = (_Float16*)(ws + (64ull << 20));  // 16 MB  [4][1024][2048]
    _Float16* xh  = (_Float16*)(ws + (80ull << 20));  // 16 MB
    _Float16* xl  = (_Float16*)(ws + (96ull << 20));  // 16 MB
    _Float16* wqh = (_Float16*)(ws + (112ull << 20)); // 2 MB
    _Float16* wkh = (_Float16*)(ws + (114ull << 20)); // 2 MB
    _Float16* wql = (_Float16*)(ws + (116ull << 20)); // 2 MB
    _Float16* wkl = (_Float16*)(ws + (118ull << 20)); // 2 MB
    _Float16* wvh = (_Float16*)(ws + (120ull << 20)); // 2 MB
    float*    sc  = (float*)(ws + (80ull << 20));     // 64 MB, overlays xh..wvh
    // total high-water: 144 MB (<= round-1's proven 160 MB)

    dim3 blk(256);

    // 1) conversions
    conv_x_kernel<<<dim3((int)(M8 / 4 / 256)), blk, 0, stream>>>(x, xh, xl, (int)(M8 / 4));
    conv_w_kernel<<<dim3(16, 16, 3), blk, 0, stream>>>(wq, wk, wv, wqh, wql, wkh, wkl, wvh);

    // 2) q,k projections (split, fused via z): A=xh/xl, B=w{q,k}T hi/lo, out f16 pairs
    gemm_split<false><<<dim3(D / BN, 8192 / BM, 2), blk, 0, stream>>>(
        xh, xl, 0, wqh, wql, M1, nullptr, 0, 0, qh, ql, M8, D, D, D, D);

    // 3) v projection (plain f16), epilogue writes vT[b][d][t] f16
    gemm_plain<true><<<dim3(D / BN, 8192 / BM, 1), blk, 0, stream>>>(
        xh, 0, wvh, 0, nullptr, 0, 0, vT, D, D, D);

    // 4) scores (split): A=qh/ql, B=kh/kl (k-contiguous), out fp32 [b][s][t]
    gemm_split<true><<<dim3(S / BN, S / BM, 4), blk, 0, stream>>>(
        qh, ql, (size_t)S * D, kh, kl, (size_t)S * D, sc, (size_t)S * S, S,
        nullptr, nullptr, 0, 0, D, D, D);

    // 5) softmax rows, f16 P written in place (row stride stays 8192 B)
    softmax_kernel<<<dim3(4 * S), blk, 0, stream>>>(sc);

    // 6) out = P @ v: A=P f16 (lda=4096 f16 elems), B=vT f16, out fp32
    gemm_plain<false><<<dim3(D / BN, S / BM, 4), blk, 0, stream>>>(
        (const _Float16*)sc, (size_t)S * 4096, vT, (size_t)D * S,
        out, (size_t)S * D, D, nullptr, 4096, S, S);
}

// Round 3
// 431.867 us; speedup vs baseline: 1.4256x; 1.0094x over previous
//
#include <hip/hip_runtime.h>

// AttentionBlock: x[4,2048,1024] fp32; scores = x@(Wq@Wk^T)@x^T (NO scale);
// softmax; out = P@(x@Wv).
// Algebraic cut: M' = Wk@Wq^T (tiny split GEMM) -> y = x@M'^T replaces BOTH
// q and k projections; scores = y@x^T reuses x hi/lo planes directly.
// Precision: split-f16 (hi+lo, 3-MFMA) for M', y, scores; plain f16 for v, PV.

typedef _Float16 half4_t __attribute__((ext_vector_type(4)));
typedef _Float16 half8_t __attribute__((ext_vector_type(8)));
typedef float f32x4 __attribute__((ext_vector_type(4)));

#define BM 128
#define BN 128
#define BK 32

__device__ __forceinline__ void gl_lds16(const _Float16* g, _Float16* l) {
    __builtin_amdgcn_global_load_lds(
        (const __attribute__((address_space(1))) unsigned int*)g,
        (__attribute__((address_space(3))) unsigned int*)l, 16, 0, 0);
}

// ---------------- conversion kernels ----------------

// fp32 -> hi/lo f16 planes (same layout). Used for x, wq, wk.
__global__ __launch_bounds__(256) void conv_split_kernel(
    const float* __restrict__ in, _Float16* __restrict__ hi,
    _Float16* __restrict__ lo, int n4)
{
    int i = blockIdx.x * 256 + threadIdx.x;
    if (i >= n4) return;
    float4 v = ((const float4*)in)[i];
    float xs[4] = {v.x, v.y, v.z, v.w};
    half4_t h, l;
#pragma unroll
    for (int j = 0; j < 4; ++j) {
        _Float16 hh = (_Float16)xs[j];
        h[j] = hh;
        l[j] = (_Float16)(xs[j] - (float)hh);
    }
    ((half4_t*)hi)[i] = h;
    ((half4_t*)lo)[i] = l;
}

// wv [1024][1024] fp32 -> wvT [1024][1024] f16 hi only. 64x64 LDS tiles.
__global__ __launch_bounds__(256) void conv_wvT_kernel(
    const float* __restrict__ w, _Float16* __restrict__ oh)
{
    __shared__ float tle[64][65];
    const int tr = blockIdx.y * 64, tc = blockIdx.x * 64;
    const int t16 = threadIdx.x & 15, tq = threadIdx.x >> 4;
#pragma unroll
    for (int j = 0; j < 4; ++j) {
        int lr = tq + j * 16;
        float4 v = *(const float4*)(w + (size_t)(tr + lr) * 1024 + tc + t16 * 4);
        tle[lr][t16 * 4 + 0] = v.x;
        tle[lr][t16 * 4 + 1] = v.y;
        tle[lr][t16 * 4 + 2] = v.z;
        tle[lr][t16 * 4 + 3] = v.w;
    }
    __syncthreads();
#pragma unroll
    for (int j = 0; j < 4; ++j) {
        int orow = tq + j * 16;
        int oc = t16 * 4;
        half4_t h;
#pragma unroll
        for (int i = 0; i < 4; ++i) h[i] = (_Float16)tle[oc + i][orow];
        *(half4_t*)(oh + (size_t)(tc + orow) * 1024 + tr + oc) = h;
    }
}

// ---------------- split-f16 GEMM (3-MFMA) ----------------
// A planes [M][K] f16, B planes [N][K] f16 (k-contiguous both).
// OUTF32: write fp32 C. else: write f16 hi/lo pair (split epilogue).
template <bool OUTF32>
__global__ __launch_bounds__(256) void gemm_split(
    const _Float16* __restrict__ Ah, const _Float16* __restrict__ Al, size_t az,
    const _Float16* __restrict__ Bh, const _Float16* __restrict__ Bl, size_t bz,
    float* __restrict__ Cf, size_t cz, int ldc,
    _Float16* __restrict__ Oh, _Float16* __restrict__ Ol, size_t oz, int ldo,
    int lda, int ldb, int K)
{
    __shared__ __align__(16) _Float16 sAh[BM][BK], sAl[BM][BK];
    __shared__ __align__(16) _Float16 sBh[BN][BK], sBl[BN][BK];

    const int tid = threadIdx.x;
    const int wave = tid >> 6, lane = tid & 63;
    const int wm = (wave >> 1) * 64, wn = (wave & 1) * 64;
    const int lrow = lane & 15, quad = lane >> 4;
    const int bm = blockIdx.y * BM, bn = blockIdx.x * BN;
    const int z = blockIdx.z;

    const _Float16* pAh = Ah + (size_t)z * az;
    const _Float16* pAl = Al + (size_t)z * az;
    const _Float16* pBh = Bh + (size_t)z * bz;
    const _Float16* pBl = Bl + (size_t)z * bz;

    const int r0 = wave * 32 + (lane >> 2);
    const int kofs = (lane & 3) * 8;
    const size_t a0o = (size_t)(bm + r0) * lda + kofs;
    const size_t a1o = a0o + (size_t)16 * lda;
    const size_t b0o = (size_t)(bn + r0) * ldb + kofs;
    const size_t b1o = b0o + (size_t)16 * ldb;
    _Float16* lA0 = &sAh[r0][kofs];
    _Float16* lA1 = &sAh[r0 + 16][kofs];
    _Float16* lAl0 = &sAl[r0][kofs];
    _Float16* lAl1 = &sAl[r0 + 16][kofs];
    _Float16* lB0 = &sBh[r0][kofs];
    _Float16* lB1 = &sBh[r0 + 16][kofs];
    _Float16* lBl0 = &sBl[r0][kofs];
    _Float16* lBl1 = &sBl[r0 + 16][kofs];

    f32x4 acc[4][4];
#pragma unroll
    for (int i = 0; i < 4; ++i)
#pragma unroll
        for (int j = 0; j < 4; ++j) acc[i][j] = 0.0f;

    for (int k0 = 0; k0 < K; k0 += BK) {
        gl_lds16(pAh + a0o + k0, lA0);
        gl_lds16(pAh + a1o + k0, lA1);
        gl_lds16(pAl + a0o + k0, lAl0);
        gl_lds16(pAl + a1o + k0, lAl1);
        gl_lds16(pBh + b0o + k0, lB0);
        gl_lds16(pBh + b1o + k0, lB1);
        gl_lds16(pBl + b0o + k0, lBl0);
        gl_lds16(pBl + b1o + k0, lBl1);
        __syncthreads();

        half8_t a0[4], a1[4], b0[4], b1[4];
#pragma unroll
        for (int mt = 0; mt < 4; ++mt) {
            a0[mt] = *(const half8_t*)&sAh[wm + mt * 16 + lrow][quad * 8];
            a1[mt] = *(const half8_t*)&sAl[wm + mt * 16 + lrow][quad * 8];
        }
#pragma unroll
        for (int nt = 0; nt < 4; ++nt) {
            b0[nt] = *(const half8_t*)&sBh[wn + nt * 16 + lrow][quad * 8];
            b1[nt] = *(const half8_t*)&sBl[wn + nt * 16 + lrow][quad * 8];
        }
#pragma unroll
        for (int mt = 0; mt < 4; ++mt)
#pragma unroll
            for (int nt = 0; nt < 4; ++nt) {
                acc[mt][nt] = __builtin_amdgcn_mfma_f32_16x16x32_f16(a0[mt], b0[nt], acc[mt][nt], 0, 0, 0);
                acc[mt][nt] = __builtin_amdgcn_mfma_f32_16x16x32_f16(a0[mt], b1[nt], acc[mt][nt], 0, 0, 0);
                acc[mt][nt] = __builtin_amdgcn_mfma_f32_16x16x32_f16(a1[mt], b0[nt], acc[mt][nt], 0, 0, 0);
            }
        __syncthreads();
    }

    // epilogue: C/D layout col=lane&15, row=quad*4+r
#pragma unroll
    for (int mt = 0; mt < 4; ++mt)
#pragma unroll
        for (int nt = 0; nt < 4; ++nt)
#pragma unroll
            for (int r = 0; r < 4; ++r) {
                int gm = bm + wm + mt * 16 + quad * 4 + r;
                int gn = bn + wn + nt * 16 + lrow;
                float v = acc[mt][nt][r];
                if (OUTF32) {
                    Cf[(size_t)z * cz + (size_t)gm * ldc + gn] = v;
                } else {
                    _Float16 h = (_Float16)v;
                    Oh[(size_t)z * oz + (size_t)gm * ldo + gn] = h;
                    Ol[(size_t)z * oz + (size_t)gm * ldo + gn] = (_Float16)(v - (float)h);
                }
            }
}

// ---------------- plain-f16 GEMM ----------------
// A [M][K] f16, B [N][K] f16. TRANSOUT: write f16 C^T per-batch as
// vT[b][n][t] (b = gm>>11, t = gm&2047); else write fp32 C row-major.
template <bool TRANSOUT>
__global__ __launch_bounds__(256) void gemm_plain(
    const _Float16* __restrict__ Ag, size_t az,
    const _Float16* __restrict__ Bg, size_t bz,
    float* __restrict__ Cf, size_t cz, int ldc,
    _Float16* __restrict__ Ot,
    int lda, int ldb, int K)
{
    __shared__ __align__(16) _Float16 sA[BM][BK], sB[BN][BK];

    const int tid = threadIdx.x;
    const int wave = tid >> 6, lane = tid & 63;
    const int wm = (wave >> 1) * 64, wn = (wave & 1) * 64;
    const int lrow = lane & 15, quad = lane >> 4;
    const int bm = blockIdx.y * BM, bn = blockIdx.x * BN;
    const int z = blockIdx.z;

    const _Float16* pA = Ag + (size_t)z * az;
    const _Float16* pB = Bg + (size_t)z * bz;

    const int r0 = wave * 32 + (lane >> 2);
    const int kofs = (lane & 3) * 8;
    const size_t a0o = (size_t)(bm + r0) * lda + kofs;
    const size_t a1o = a0o + (size_t)16 * lda;
    const size_t b0o = (size_t)(bn + r0) * ldb + kofs;
    const size_t b1o = b0o + (size_t)16 * ldb;
    _Float16* lA0 = &sA[r0][kofs];
    _Float16* lA1 = &sA[r0 + 16][kofs];
    _Float16* lB0 = &sB[r0][kofs];
    _Float16* lB1 = &sB[r0 + 16][kofs];

    f32x4 acc[4][4];
#pragma unroll
    for (int i = 0; i < 4; ++i)
#pragma unroll
        for (int j = 0; j < 4; ++j) acc[i][j] = 0.0f;

    for (int k0 = 0; k0 < K; k0 += BK) {
        gl_lds16(pA + a0o + k0, lA0);
        gl_lds16(pA + a1o + k0, lA1);
        gl_lds16(pB + b0o + k0, lB0);
        gl_lds16(pB + b1o + k0, lB1);
        __syncthreads();

        half8_t a0[4], b0[4];
#pragma unroll
        for (int mt = 0; mt < 4; ++mt)
            a0[mt] = *(const half8_t*)&sA[wm + mt * 16 + lrow][quad * 8];
#pragma unroll
        for (int nt = 0; nt < 4; ++nt)
            b0[nt] = *(const half8_t*)&sB[wn + nt * 16 + lrow][quad * 8];
#pragma unroll
        for (int mt = 0; mt < 4; ++mt)
#pragma unroll
            for (int nt = 0; nt < 4; ++nt)
                acc[mt][nt] = __builtin_amdgcn_mfma_f32_16x16x32_f16(a0[mt], b0[nt], acc[mt][nt], 0, 0, 0);
        __syncthreads();
    }

#pragma unroll
    for (int mt = 0; mt < 4; ++mt)
#pragma unroll
        for (int nt = 0; nt < 4; ++nt) {
            int gm0 = bm + wm + mt * 16 + quad * 4;
            int gn = bn + wn + nt * 16 + lrow;
            if (TRANSOUT) {
                half4_t o;
#pragma unroll
                for (int r = 0; r < 4; ++r) o[r] = (_Float16)acc[mt][nt][r];
                *(half4_t*)(Ot + ((size_t)(gm0 >> 11) << 21) +
                            (size_t)gn * 2048 + (gm0 & 2047)) = o;
            } else {
#pragma unroll
                for (int r = 0; r < 4; ++r)
                    Cf[(size_t)z * cz + (size_t)(gm0 + r) * ldc + gn] = acc[mt][nt][r];
            }
        }
}

// ---------------- softmax: fp32 scores row -> f16 P row, in place ----------------
__global__ __launch_bounds__(256) void softmax_kernel(float* __restrict__ S)
{
    float* row = S + (size_t)blockIdx.x * 2048;
    float4* r4 = (float4*)row;
    const int tid = threadIdx.x;
    const int wave = tid >> 6, lane = tid & 63;

    float4 a = r4[tid], b = r4[tid + 256];
    float m = fmaxf(fmaxf(fmaxf(a.x, a.y), fmaxf(a.z, a.w)),
                    fmaxf(fmaxf(b.x, b.y), fmaxf(b.z, b.w)));
#pragma unroll
    for (int o = 32; o; o >>= 1) m = fmaxf(m, __shfl_xor(m, o));
    __shared__ float redm[4];
    __shared__ float reds[4];
    if (lane == 0) redm[wave] = m;
    __syncthreads();
    m = fmaxf(fmaxf(redm[0], redm[1]), fmaxf(redm[2], redm[3]));

    a.x = __expf(a.x - m); a.y = __expf(a.y - m);
    a.z = __expf(a.z - m); a.w = __expf(a.w - m);
    b.x = __expf(b.x - m); b.y = __expf(b.y - m);
    b.z = __expf(b.z - m); b.w = __expf(b.w - m);

    float s = a.x + a.y + a.z + a.w + b.x + b.y + b.z + b.w;
#pragma unroll
    for (int o = 32; o; o >>= 1) s += __shfl_xor(s, o);
    if (lane == 0) reds[wave] = s;
    __syncthreads();   // also orders all row loads before the f16 overwrite below
    s = reds[0] + reds[1] + reds[2] + reds[3];

    float inv = 1.0f / s;
    _Float16* o16 = (_Float16*)row;
    half4_t ha, hb;
    ha[0] = (_Float16)(a.x * inv); ha[1] = (_Float16)(a.y * inv);
    ha[2] = (_Float16)(a.z * inv); ha[3] = (_Float16)(a.w * inv);
    hb[0] = (_Float16)(b.x * inv); hb[1] = (_Float16)(b.y * inv);
    hb[2] = (_Float16)(b.z * inv); hb[3] = (_Float16)(b.w * inv);
    ((half4_t*)o16)[tid] = ha;
    ((half4_t*)o16)[tid + 256] = hb;
}

extern "C" void kernel_launch(void* const* d_in, const int* in_sizes, int n_in,
                              void* d_out, int out_size, void* d_ws, size_t ws_size,
                              hipStream_t stream)
{
    const float* x  = (const float*)d_in[0];
    const float* wq = (const float*)d_in[1];
    const float* wk = (const float*)d_in[2];
    const float* wv = (const float*)d_in[3];
    float* out = (float*)d_out;

    const int S = 2048, D = 1024;
    const size_t M8 = 8ull << 20;  // 8192x1024 elems
    const size_t M1 = 1ull << 20;  // 1024x1024 elems
    char* ws = (char*)d_ws;

    // ws layout (bytes); high-water 158 MB (round-1 proved >=160 MB available)
    _Float16* xh   = (_Float16*)(ws);                  // 16 MB
    _Float16* xl   = (_Float16*)(ws + (16ull << 20));  // 16 MB
    _Float16* yh   = (_Float16*)(ws + (32ull << 20));  // 16 MB
    _Float16* yl   = (_Float16*)(ws + (48ull << 20));  // 16 MB
    _Float16* vT   = (_Float16*)(ws + (64ull << 20));  // 16 MB [4][1024][2048]
    _Float16* wqh  = (_Float16*)(ws + (80ull << 20));  // 2 MB (natural layout)
    _Float16* wql  = (_Float16*)(ws + (82ull << 20));  // 2 MB
    _Float16* wkh  = (_Float16*)(ws + (84ull << 20));  // 2 MB
    _Float16* wkl  = (_Float16*)(ws + (86ull << 20));  // 2 MB
    _Float16* wvTh = (_Float16*)(ws + (88ull << 20));  // 2 MB (transposed)
    _Float16* Mh   = (_Float16*)(ws + (90ull << 20));  // 2 MB  M' = Wk@Wq^T
    _Float16* Ml   = (_Float16*)(ws + (92ull << 20));  // 2 MB
    float*    sc   = (float*)(ws + (94ull << 20));     // 64 MB scores

    dim3 blk(256);

    // 1) conversions: x, wq, wk -> hi/lo planes (natural layout); wv -> wvT hi
    conv_split_kernel<<<dim3((int)(M8 / 4 / 256)), blk, 0, stream>>>(x, xh, xl, (int)(M8 / 4));
    conv_split_kernel<<<dim3((int)(M1 / 4 / 256)), blk, 0, stream>>>(wq, wqh, wql, (int)(M1 / 4));
    conv_split_kernel<<<dim3((int)(M1 / 4 / 256)), blk, 0, stream>>>(wk, wkh, wkl, (int)(M1 / 4));
    conv_wvT_kernel<<<dim3(16, 16), blk, 0, stream>>>(wv, wvTh);

    // 2) M'[d'][d] = sum_e Wk[d',e]*Wq[d,e]  (split in, split out)
    gemm_split<false><<<dim3(8, 8, 1), blk, 0, stream>>>(
        wkh, wkl, 0, wqh, wql, 0, nullptr, 0, 0, Mh, Ml, 0, D, D, D, D);

    // 3) y[s][d'] = sum_d x[s,d]*M'[d',d]  (split in, split out) — replaces q AND k proj
    gemm_split<false><<<dim3(D / BN, 8192 / BM, 1), blk, 0, stream>>>(
        xh, xl, 0, Mh, Ml, 0, nullptr, 0, 0, yh, yl, 0, D, D, D, D);

    // 4) v projection (plain f16), epilogue writes vT[b][d][t] f16
    gemm_plain<true><<<dim3(D / BN, 8192 / BM, 1), blk, 0, stream>>>(
        xh, 0, wvTh, 0, nullptr, 0, 0, vT, D, D, D);

    // 5) scores[b][s][t] = sum_d' y[b,s,d']*x[b,t,d']  (split), out fp32
    gemm_split<true><<<dim3(S / BN, S / BM, 4), blk, 0, stream>>>(
        yh, yl, (size_t)S * D, xh, xl, (size_t)S * D, sc, (size_t)S * S, S,
        nullptr, nullptr, 0, 0, D, D, D);

    // 6) softmax rows, f16 P written in place (row stride stays 8192 B)
    softmax_kernel<<<dim3(4 * S), blk, 0, stream>>>(sc);

    // 7) out = P @ v: A=P f16 (lda=4096 f16 elems), B=vT f16, out fp32
    gemm_plain<false><<<dim3(D / BN, S / BM, 4), blk, 0, stream>>>(
        (const _Float16*)sc, (size_t)S * 4096, vT, (size_t)D * S,
        out, (size_t)S * D, D, nullptr, 4096, S, S);
}